// Round 20
// baseline (185.745 us; speedup 1.0000x reference)
//
#include <hip/hip_runtime.h>
#include <math.h>

#define N 8192
#define D 256
#define NCH 64                 // column chunks (grid.y)
#define RB 256                 // rows per block (4 waves x 64)
#define RT 4                   // row-tiles of 16 per wave
#define CHUNK (N / NCH)        // 128 cols per chunk
#define NCT (CHUNK / 16)       // 8 col-tiles of 16

constexpr float MARGIN = 0.3f;
constexpr float EPS_PAIR = 1e-6f;
constexpr float BIAS = 512.0f;

typedef float f32x4 __attribute__((ext_vector_type(4)));
typedef int   i32x4 __attribute__((ext_vector_type(4)));
typedef int   i32x8 __attribute__((ext_vector_type(8)));

// ---------- helpers ----------
__device__ __forceinline__ void load_lds16(const void* g, void* l) {
  __builtin_amdgcn_global_load_lds((const __attribute__((address_space(1))) void*)g,
                                   (__attribute__((address_space(3))) void*)l, 16, 0, 0);
}

__device__ __forceinline__ unsigned umin(unsigned a, unsigned b) { return a < b ? a : b; }
__device__ __forceinline__ unsigned umax(unsigned a, unsigned b) { return a > b ? a : b; }

// merge sorted pair (w1<=w2) into sorted running top-2 (v1<=v2), all packed u32
__device__ __forceinline__ void top2merge(unsigned& v1, unsigned& v2,
                                          unsigned w1, unsigned w2) {
  unsigned mx = umax(v1, w1);
  v1 = umin(v1, w1);
  v2 = umin(v2, umin(mx, w2));   // v_min3_u32
}

// DPP lane exchange (VALU pipe, row-of-16 scope); CTRL immediate via template.
template <int CTRL>
__device__ __forceinline__ unsigned dppx(unsigned v) {
  return (unsigned)__builtin_amdgcn_update_dpp(0, (int)v, CTRL, 0xF, 0xF, true);
}

template <int CTRL>
__device__ __forceinline__ void dpp_merge(unsigned& a1, unsigned& a2) {
  unsigned w1 = dppx<CTRL>(a1);
  unsigned w2 = dppx<CTRL>(a2);
  top2merge(a1, a2, w1, w2);
}

// ---------- kernel 0: fused fp8(e4m3) convert + scaled row norms ----------
// sqh[i] = -0.5*(sq[i] + BIAS): MFMA accumulator init, so acc_final = -(score)/2.
// All accs negative; u32 compare on the packed bits ranks identically to
// ascending score (magnitude-monotone), ties -> smaller index.
__global__ void prep_kernel(const float* __restrict__ in, char* __restrict__ A8,
                            float* __restrict__ sqh) {
  int row  = blockIdx.x * 4 + (threadIdx.x >> 6);
  int lane = threadIdx.x & 63;
  float4 v = ((const float4*)(in + (size_t)row * D))[lane];
  int w = 0;
  w = __builtin_amdgcn_cvt_pk_fp8_f32(v.x, v.y, w, false);  // bytes 0,1
  w = __builtin_amdgcn_cvt_pk_fp8_f32(v.z, v.w, w, true);   // bytes 2,3
  *(int*)(A8 + (size_t)row * D + lane * 4) = w;
  float s = v.x * v.x + v.y * v.y + v.z * v.z + v.w * v.w;
#pragma unroll
  for (int m = 32; m; m >>= 1) s += __shfl_xor(s, m);
  if (lane == 0) sqh[row] = -0.5f * (s + BIAS);
}

// ---------- kernel 1: MX-fp8 MFMA Gram + packed-u32 per-row top-2 ----------
// 32KB chunk staged up front, ONE barrier, fully-unrolled barrier-free loop
// (static sqreg index), DPP epilogue; 3 blocks/CU.
__global__ __launch_bounds__(256, 3) void neighbor_kernel(
    const char* __restrict__ A8, const float* __restrict__ sqh,
    uint2* __restrict__ pp) {
  __shared__ __attribute__((aligned(16))) char ldsB[CHUNK * 256];  // 32 KB

  const int t = threadIdx.x;
  const int lane = t & 63;
  const int wave = t >> 6;
  const int rowBase = blockIdx.x * RB + wave * 64;   // this wave's 64 rows
  const int colBase = blockIdx.y * CHUNK;

  const int lrow = lane & 15;    // A row / B col within 16-tile
  const int lkg  = lane >> 4;    // k-group 0..3 (32 fp8 each)

  // ---- stage the whole chunk: linear LDS dest, inverse-swizzled global src
  {
    int r0 = t >> 4;                       // col within first 16-col slab
    int o0 = (t & 15) * 16;                // byte within 256B col
    const char* src = A8 + (size_t)(colBase + r0) * 256 + (o0 ^ ((r0 & 7) << 4));
#pragma unroll
    for (int it = 0; it < NCT; ++it) {
      load_lds16(src, &ldsB[it * 4096 + t * 16]);
      src += 4096;   // +16 cols
    }
  }

  // ---- A fragments: 4 row-tiles x 2 k-steps x 32 fp8 (64 VGPRs)
  i32x8 afrag[RT][2];
#pragma unroll
  for (int rt = 0; rt < RT; ++rt) {
    const char* arow = A8 + (size_t)(rowBase + rt * 16 + lrow) * D;
#pragma unroll
    for (int ks = 0; ks < 2; ++ks)
      afrag[rt][ks] = *(const i32x8*)(arow + ks * 128 + lkg * 32);
  }

  // ---- per-lane acc-init values in REGISTERS (static index after unroll)
  float sqreg[NCT];
#pragma unroll
  for (int ct = 0; ct < NCT; ++ct) sqreg[ct] = sqh[colBase + ct * 16 + lrow];

  // ---- loop-invariant swizzled ds_read byte offsets (16B granule)
  int dsoff[4];
#pragma unroll
  for (int ks = 0; ks < 2; ++ks)
#pragma unroll
    for (int h = 0; h < 2; ++h)
      dsoff[ks * 2 + h] = lrow * 256 + ((ks * 128 + lkg * 32 + h * 16) ^ ((lrow & 7) << 4));

  // ---- packed running top-2 per (rt,q): score19 | idx13
  unsigned v1[RT][4], v2[RT][4];
#pragma unroll
  for (int rt = 0; rt < RT; ++rt)
#pragma unroll
    for (int q = 0; q < 4; ++q) { v1[rt][q] = 0xFFFFFFFFu; v2[rt][q] = 0xFFFFFFFFu; }

  __syncthreads();   // the ONLY barrier: staged chunk visible to all

#pragma unroll
  for (int ct = 0; ct < NCT; ++ct) {
    const char* bt = ldsB + ct * 4096;
    const float sqv = sqreg[ct];
    f32x4 acc[RT];
#pragma unroll
    for (int rt = 0; rt < RT; ++rt) acc[rt] = (f32x4){sqv, sqv, sqv, sqv};

    __builtin_amdgcn_s_setprio(1);
#pragma unroll
    for (int ks = 0; ks < 2; ++ks) {
      i32x4 lo = *(const i32x4*)(bt + dsoff[ks * 2]);
      i32x4 hi = *(const i32x4*)(bt + dsoff[ks * 2 + 1]);
      i32x8 bfrag = __builtin_shufflevector(lo, hi, 0, 1, 2, 3, 4, 5, 6, 7);
#pragma unroll
      for (int rt = 0; rt < RT; ++rt)
        acc[rt] = __builtin_amdgcn_mfma_scale_f32_16x16x128_f8f6f4(
            afrag[rt][ks], bfrag, acc[rt], 0, 0,
            0, 0x7F7F7F7F, 0, 0x7F7F7F7F);   // fp8 fmt, scales = 1.0
    }
    __builtin_amdgcn_s_setprio(0);

    const int j = colBase + ct * 16 + lrow;
#pragma unroll
    for (int rt = 0; rt < RT; ++rt) {
      const bool diag = (colBase + ct * 16) == (rowBase + rt * 16);  // wave-uniform
#pragma unroll
      for (int q = 0; q < 4; ++q) {
        unsigned p = (__float_as_uint(acc[rt][q]) & 0xFFFFE000u) | (unsigned)j;
        if (diag) p = (lrow == lkg * 4 + q) ? 0xFFFFFFFFu : p;  // exclude self
        unsigned mx = umax(v1[rt][q], p);
        v1[rt][q] = umin(v1[rt][q], p);
        v2[rt][q] = umin(v2[rt][q], mx);
      }
    }
  }

  // ---- cross-lane merge over the 16 lanes sharing a row via DPP (VALU pipe)
#pragma unroll
  for (int rt = 0; rt < RT; ++rt) {
#pragma unroll
    for (int q = 0; q < 4; ++q) {
      unsigned a1 = v1[rt][q], a2 = v2[rt][q];
      dpp_merge<0xB1>(a1, a2);    // quad_perm(1,0,3,2)  : xor 1
      dpp_merge<0x4E>(a1, a2);    // quad_perm(2,3,0,1)  : xor 2
      dpp_merge<0x141>(a1, a2);   // row_half_mirror     : xor 4 (quads uniform)
      dpp_merge<0x140>(a1, a2);   // row_mirror          : xor 8 (halves uniform)
      if (lrow == 0) {
        int ig = rowBase + rt * 16 + lkg * 4 + q;
        pp[(size_t)blockIdx.y * N + ig] = make_uint2(a1, a2);
      }
    }
  }
}

// ---------- kernel 2: fused chunk-merge + triplet hinge ----------
__global__ void finish_kernel(const float* __restrict__ A, const float* __restrict__ P,
                              const uint2* __restrict__ pp, float* __restrict__ rowLoss) {
  int row  = blockIdx.x * 4 + (threadIdx.x >> 6);
  int lane = threadIdx.x & 63;

  // merge the 64 chunk partials (one per lane) via full-wave butterfly
  uint2 pr = pp[(size_t)lane * N + row];
  unsigned a1 = pr.x, a2 = pr.y;
#pragma unroll
  for (int m = 1; m < 64; m <<= 1) {
    unsigned w1 = (unsigned)__shfl_xor((int)a1, m);
    unsigned w2 = (unsigned)__shfl_xor((int)a2, m);
    top2merge(a1, a2, w1, w2);
  }
  int nr = (int)(a2 & 0x1FFFu);   // 2nd-smallest among j != i == reference idx3[:,2]

  float4 av = ((const float4*)(A + (size_t)row * D))[lane];
  float4 pv = ((const float4*)(P + (size_t)row * D))[lane];
  float4 gv = ((const float4*)(A + (size_t)nr  * D))[lane];
  float dap = 0.f, dan = 0.f, x;
  x = av.x - pv.x + EPS_PAIR; dap += x * x;
  x = av.y - pv.y + EPS_PAIR; dap += x * x;
  x = av.z - pv.z + EPS_PAIR; dap += x * x;
  x = av.w - pv.w + EPS_PAIR; dap += x * x;
  x = av.x - gv.x + EPS_PAIR; dan += x * x;
  x = av.y - gv.y + EPS_PAIR; dan += x * x;
  x = av.z - gv.z + EPS_PAIR; dan += x * x;
  x = av.w - gv.w + EPS_PAIR; dan += x * x;
#pragma unroll
  for (int m = 32; m; m >>= 1) {
    dap += __shfl_xor(dap, m);
    dan += __shfl_xor(dan, m);
  }
  if (lane == 0)
    rowLoss[row] = fmaxf(sqrtf(dap) - sqrtf(dan) + MARGIN, 0.f);
}

// ---------- kernel 3: deterministic mean reduction ----------
__global__ void reduce_kernel(const float* __restrict__ rowLoss, float* __restrict__ out) {
  __shared__ float smem[256];
  int t = threadIdx.x;
  float s = 0.f;
  for (int i = t; i < N; i += 256) s += rowLoss[i];
  smem[t] = s;
  __syncthreads();
  for (int stride = 128; stride; stride >>= 1) {
    if (t < stride) smem[t] += smem[t + stride];
    __syncthreads();
  }
  if (t == 0) out[0] = smem[0] * (1.0f / (float)N);
}

// ---------- launch ----------
extern "C" void kernel_launch(void* const* d_in, const int* in_sizes, int n_in,
                              void* d_out, int out_size, void* d_ws, size_t ws_size,
                              hipStream_t stream) {
  const float* inputs   = (const float*)d_in[0];
  const float* positive = (const float*)d_in[1];
  float* out = (float*)d_out;

  // ws layout (~6.2 MB)
  char*  A8      = (char*)d_ws;                        // N*D fp8 (2 MB)
  float* sqh     = (float*)(A8 + (size_t)N * D);       // N
  uint2* pp      = (uint2*)(sqh + N);                  // NCH*N uint2 (4 MB)
  float* rowLoss = (float*)(pp + (size_t)NCH * N);     // N

  prep_kernel<<<N / 4, 256, 0, stream>>>(inputs, A8, sqh);
  neighbor_kernel<<<dim3(N / RB, NCH), 256, 0, stream>>>(A8, sqh, pp);
  finish_kernel<<<N / 4, 256, 0, stream>>>(inputs, positive, pp, rowLoss);
  reduce_kernel<<<1, 256, 0, stream>>>(rowLoss, out);
}

// Round 21
// 49.651 us; speedup vs baseline: 3.7410x; 3.7410x over previous
//
#include <hip/hip_runtime.h>
#include <math.h>

#define N 8192
#define D 256
#define NCH 32                 // column chunks (grid.y)
#define RB 256                 // rows per block (4 waves x 64)
#define RT 4                   // row-tiles of 16 per wave
#define CHUNK (N / NCH)        // 256 cols per chunk
#define NCT (CHUNK / 16)       // 16 col-tiles of 16

constexpr float MARGIN = 0.3f;
constexpr float EPS_PAIR = 1e-6f;
constexpr float BIAS = 512.0f;

typedef float f32x4 __attribute__((ext_vector_type(4)));
typedef int   i32x4 __attribute__((ext_vector_type(4)));
typedef int   i32x8 __attribute__((ext_vector_type(8)));

// ---------- helpers ----------
__device__ __forceinline__ void load_lds16(const void* g, void* l) {
  __builtin_amdgcn_global_load_lds((const __attribute__((address_space(1))) void*)g,
                                   (__attribute__((address_space(3))) void*)l, 16, 0, 0);
}

__device__ __forceinline__ unsigned umin(unsigned a, unsigned b) { return a < b ? a : b; }
__device__ __forceinline__ unsigned umax(unsigned a, unsigned b) { return a > b ? a : b; }

// merge sorted pair (w1<=w2) into sorted running top-2 (v1<=v2), all packed u32
__device__ __forceinline__ void top2merge(unsigned& v1, unsigned& v2,
                                          unsigned w1, unsigned w2) {
  unsigned mx = umax(v1, w1);
  v1 = umin(v1, w1);
  v2 = umin(v2, umin(mx, w2));   // v_min3_u32 candidate
}

// DPP lane exchange (VALU pipe, row-of-16 scope); CTRL must be an immediate ->
// template parameter guarantees a constant at the builtin call site.
template <int CTRL>
__device__ __forceinline__ unsigned dppx(unsigned v) {
  return (unsigned)__builtin_amdgcn_update_dpp(0, (int)v, CTRL, 0xF, 0xF, true);
}

// one DPP butterfly step on the (v1,v2) running top-2
template <int CTRL>
__device__ __forceinline__ void dpp_merge(unsigned& a1, unsigned& a2) {
  unsigned w1 = dppx<CTRL>(a1);
  unsigned w2 = dppx<CTRL>(a2);
  top2merge(a1, a2, w1, w2);
}

// ---------- kernel 0: fused fp8(e4m3) convert + scaled row norms ----------
// sqh[i] = -0.5*(sq[i] + BIAS): MFMA accumulator init, so acc_final = -(score)/2.
// All accs negative; u32 compare on the packed bits ranks identically to
// ascending score (magnitude-monotone), ties -> smaller index.
__global__ void prep_kernel(const float* __restrict__ in, char* __restrict__ A8,
                            float* __restrict__ sqh) {
  int row  = blockIdx.x * 4 + (threadIdx.x >> 6);
  int lane = threadIdx.x & 63;
  float4 v = ((const float4*)(in + (size_t)row * D))[lane];
  int w = 0;
  w = __builtin_amdgcn_cvt_pk_fp8_f32(v.x, v.y, w, false);  // bytes 0,1
  w = __builtin_amdgcn_cvt_pk_fp8_f32(v.z, v.w, w, true);   // bytes 2,3
  *(int*)(A8 + (size_t)row * D + lane * 4) = w;
  float s = v.x * v.x + v.y * v.y + v.z * v.z + v.w * v.w;
#pragma unroll
  for (int m = 32; m; m >>= 1) s += __shfl_xor(s, m);
  if (lane == 0) sqh[row] = -0.5f * (s + BIAS);
}

// ---------- kernel 1: MX-fp8 MFMA Gram + packed-u32 per-row top-2 ----------
// Whole 64KB chunk staged into LDS up front, ONE barrier, barrier-free loop;
// unroll-4 window + setprio'd MFMA cluster + DPP (VALU-pipe) epilogue merge.
// NOTE: 2 blocks/CU (cap 256 VGPR) is required -- bounds(256,3) spills afrag
// (measured r10/r20: VGPR=84 + 239MB scratch writes).
__global__ __launch_bounds__(256, 2) void neighbor_kernel(
    const char* __restrict__ A8, const float* __restrict__ sqh,
    uint2* __restrict__ pp) {
  __shared__ __attribute__((aligned(16))) char ldsB[CHUNK * 256];  // 64 KB
  __shared__ float ldsSq[CHUNK];

  const int t = threadIdx.x;
  const int lane = t & 63;
  const int wave = t >> 6;
  const int rowBase = blockIdx.x * RB + wave * 64;   // this wave's 64 rows
  const int colBase = blockIdx.y * CHUNK;

  const int lrow = lane & 15;    // A row / B col within 16-tile
  const int lkg  = lane >> 4;    // k-group 0..3 (32 fp8 each)

  // ---- stage the whole chunk: linear LDS dest, inverse-swizzled global src
  {
    int r0 = t >> 4;                       // col within first 16-col slab
    int o0 = (t & 15) * 16;                // byte within 256B col
    const char* src = A8 + (size_t)(colBase + r0) * 256 + (o0 ^ ((r0 & 7) << 4));
#pragma unroll
    for (int it = 0; it < NCT; ++it) {
      load_lds16(src, &ldsB[it * 4096 + t * 16]);
      src += 4096;   // +16 cols
    }
  }

  // ---- A fragments: 4 row-tiles x 2 k-steps x 32 fp8 (64 VGPRs)
  i32x8 afrag[RT][2];
#pragma unroll
  for (int rt = 0; rt < RT; ++rt) {
    const char* arow = A8 + (size_t)(rowBase + rt * 16 + lrow) * D;
#pragma unroll
    for (int ks = 0; ks < 2; ++ks)
      afrag[rt][ks] = *(const i32x8*)(arow + ks * 128 + lkg * 32);
  }

  // ---- preload chunk's acc-init values into LDS
  if (t < CHUNK) ldsSq[t] = sqh[colBase + t];

  // ---- loop-invariant swizzled ds_read byte offsets (16B granule)
  int dsoff[4];
#pragma unroll
  for (int ks = 0; ks < 2; ++ks)
#pragma unroll
    for (int h = 0; h < 2; ++h)
      dsoff[ks * 2 + h] = lrow * 256 + ((ks * 128 + lkg * 32 + h * 16) ^ ((lrow & 7) << 4));

  // ---- packed running top-2 per (rt,q): score19 | idx13
  unsigned v1[RT][4], v2[RT][4];
#pragma unroll
  for (int rt = 0; rt < RT; ++rt)
#pragma unroll
    for (int q = 0; q < 4; ++q) { v1[rt][q] = 0xFFFFFFFFu; v2[rt][q] = 0xFFFFFFFFu; }

  __syncthreads();   // the ONLY barrier: staged chunk + ldsSq visible to all

#pragma unroll 4
  for (int ct = 0; ct < NCT; ++ct) {
    const char* bt = ldsB + ct * 4096;
    const float sqv = ldsSq[ct * 16 + lrow];
    f32x4 acc[RT];
#pragma unroll
    for (int rt = 0; rt < RT; ++rt) acc[rt] = (f32x4){sqv, sqv, sqv, sqv};

    __builtin_amdgcn_s_setprio(1);
#pragma unroll
    for (int ks = 0; ks < 2; ++ks) {
      i32x4 lo = *(const i32x4*)(bt + dsoff[ks * 2]);
      i32x4 hi = *(const i32x4*)(bt + dsoff[ks * 2 + 1]);
      i32x8 bfrag = __builtin_shufflevector(lo, hi, 0, 1, 2, 3, 4, 5, 6, 7);
#pragma unroll
      for (int rt = 0; rt < RT; ++rt)
        acc[rt] = __builtin_amdgcn_mfma_scale_f32_16x16x128_f8f6f4(
            afrag[rt][ks], bfrag, acc[rt], 0, 0,
            0, 0x7F7F7F7F, 0, 0x7F7F7F7F);   // fp8 fmt, scales = 1.0
    }
    __builtin_amdgcn_s_setprio(0);

    const int j = colBase + ct * 16 + lrow;
#pragma unroll
    for (int rt = 0; rt < RT; ++rt) {
      const bool diag = (colBase + ct * 16) == (rowBase + rt * 16);  // wave-uniform
#pragma unroll
      for (int q = 0; q < 4; ++q) {
        unsigned p = (__float_as_uint(acc[rt][q]) & 0xFFFFE000u) | (unsigned)j;
        if (diag) p = (lrow == lkg * 4 + q) ? 0xFFFFFFFFu : p;  // exclude self
        unsigned mx = umax(v1[rt][q], p);
        v1[rt][q] = umin(v1[rt][q], p);
        v2[rt][q] = umin(v2[rt][q], mx);
      }
    }
  }

  // ---- cross-lane merge over the 16 lanes sharing a row via DPP (VALU pipe):
  // xor1 = quad_perm(1,0,3,2)=0xB1; xor2 = quad_perm(2,3,0,1)=0x4E; after these
  // each quad is uniform, so row_half_mirror (0x141, i->7-i) merges quad pairs
  // and row_mirror (0x140, i->15-i) merges halves. All within the 16-lane row.
#pragma unroll
  for (int rt = 0; rt < RT; ++rt) {
#pragma unroll
    for (int q = 0; q < 4; ++q) {
      unsigned a1 = v1[rt][q], a2 = v2[rt][q];
      dpp_merge<0xB1>(a1, a2);    // quad_perm(1,0,3,2)  : xor 1
      dpp_merge<0x4E>(a1, a2);    // quad_perm(2,3,0,1)  : xor 2
      dpp_merge<0x141>(a1, a2);   // row_half_mirror     : xor 4 (quads uniform)
      dpp_merge<0x140>(a1, a2);   // row_mirror          : xor 8 (halves uniform)
      if (lrow == 0) {
        int ig = rowBase + rt * 16 + lkg * 4 + q;
        pp[(size_t)blockIdx.y * N + ig] = make_uint2(a1, a2);
      }
    }
  }
}

// ---------- kernel 2: fused chunk-merge + triplet hinge ----------
__global__ void finish_kernel(const float* __restrict__ A, const float* __restrict__ P,
                              const uint2* __restrict__ pp, float* __restrict__ rowLoss) {
  int row  = blockIdx.x * 4 + (threadIdx.x >> 6);
  int lane = threadIdx.x & 63;

  // merge the 32 chunk partials (lanes 32-63 mirror lanes 0-31)
  uint2 pr = pp[(size_t)(lane & 31) * N + row];
  unsigned a1 = pr.x, a2 = pr.y;
#pragma unroll
  for (int m = 1; m < 32; m <<= 1) {
    unsigned w1 = (unsigned)__shfl_xor((int)a1, m);
    unsigned w2 = (unsigned)__shfl_xor((int)a2, m);
    top2merge(a1, a2, w1, w2);
  }
  int nr = (int)(a2 & 0x1FFFu);   // 2nd-smallest among j != i == reference idx3[:,2]

  float4 av = ((const float4*)(A + (size_t)row * D))[lane];
  float4 pv = ((const float4*)(P + (size_t)row * D))[lane];
  float4 gv = ((const float4*)(A + (size_t)nr  * D))[lane];
  float dap = 0.f, dan = 0.f, x;
  x = av.x - pv.x + EPS_PAIR; dap += x * x;
  x = av.y - pv.y + EPS_PAIR; dap += x * x;
  x = av.z - pv.z + EPS_PAIR; dap += x * x;
  x = av.w - pv.w + EPS_PAIR; dap += x * x;
  x = av.x - gv.x + EPS_PAIR; dan += x * x;
  x = av.y - gv.y + EPS_PAIR; dan += x * x;
  x = av.z - gv.z + EPS_PAIR; dan += x * x;
  x = av.w - gv.w + EPS_PAIR; dan += x * x;
#pragma unroll
  for (int m = 32; m; m >>= 1) {
    dap += __shfl_xor(dap, m);
    dan += __shfl_xor(dan, m);
  }
  if (lane == 0)
    rowLoss[row] = fmaxf(sqrtf(dap) - sqrtf(dan) + MARGIN, 0.f);
}

// ---------- kernel 3: deterministic mean reduction ----------
__global__ void reduce_kernel(const float* __restrict__ rowLoss, float* __restrict__ out) {
  __shared__ float smem[256];
  int t = threadIdx.x;
  float s = 0.f;
  for (int i = t; i < N; i += 256) s += rowLoss[i];
  smem[t] = s;
  __syncthreads();
  for (int stride = 128; stride; stride >>= 1) {
    if (t < stride) smem[t] += smem[t + stride];
    __syncthreads();
  }
  if (t == 0) out[0] = smem[0] * (1.0f / (float)N);
}

// ---------- launch ----------
extern "C" void kernel_launch(void* const* d_in, const int* in_sizes, int n_in,
                              void* d_out, int out_size, void* d_ws, size_t ws_size,
                              hipStream_t stream) {
  const float* inputs   = (const float*)d_in[0];
  const float* positive = (const float*)d_in[1];
  float* out = (float*)d_out;

  // ws layout (~4.3 MB)
  char*  A8      = (char*)d_ws;                        // N*D fp8 (2 MB)
  float* sqh     = (float*)(A8 + (size_t)N * D);       // N
  uint2* pp      = (uint2*)(sqh + N);                  // NCH*N uint2 (2 MB)
  float* rowLoss = (float*)(pp + (size_t)NCH * N);     // N

  prep_kernel<<<N / 4, 256, 0, stream>>>(inputs, A8, sqh);
  neighbor_kernel<<<dim3(N / RB, NCH), 256, 0, stream>>>(A8, sqh, pp);
  finish_kernel<<<N / 4, 256, 0, stream>>>(inputs, positive, pp, rowLoss);
  reduce_kernel<<<1, 256, 0, stream>>>(rowLoss, out);
}